// Round 3
// baseline (15894.769 us; speedup 1.0000x reference)
//
#include <hip/hip_runtime.h>

#define T_STEPS 512
#define BB 64
#define EE 300
#define EP 320
#define HH 512
#define G3 1536
#define HB (BB*HH)   // halves per h slot
#define RING 4

typedef _Float16 f16x8 __attribute__((ext_vector_type(8)));
typedef float f32x4 __attribute__((ext_vector_type(4)));
typedef int i32x4 __attribute__((ext_vector_type(4)));
typedef unsigned long long u64;

#define MEMBAR() asm volatile("" ::: "memory")

__device__ __forceinline__ f32x4 mf(f16x8 a, f16x8 b, f32x4 c) {
  return __builtin_amdgcn_mfma_f32_16x16x32_f16(a, b, c, 0, 0, 0);
}

// LLC-coherent (cross-XCD) 8B load; relaxed agent scope -> sc1 bypass of L1/L2
__device__ __forceinline__ u64 ld8_llc(const u64* p) {
  return __hip_atomic_load(p, __ATOMIC_RELAXED, __HIP_MEMORY_SCOPE_AGENT);
}

// LLC-coherent 16B store (coalesced)
__device__ __forceinline__ void st16_llc(void* p, f16x8 v) {
  i32x4 iv;
  __builtin_memcpy(&iv, &v, 16);
  asm volatile("global_store_dwordx4 %0, %1, off sc0 sc1" :: "v"(p), "v"(iv) : "memory");
}

// flag publish: plain byte store at LLC (no RMW!)
__device__ __forceinline__ void st1_llc(char* p, int v) {
  asm volatile("global_store_byte %0, %1, off sc0 sc1" :: "v"(p), "v"(v) : "memory");
}

// fresh 4B poll load from LLC
__device__ __forceinline__ int ld4_poll(const int* p) {
  int r;
  asm volatile("global_load_dword %0, %1, off sc1\n\ts_waitcnt vmcnt(0)"
               : "=v"(r) : "v"(p) : "memory");
  return r;
}

// wait until all 32 WG-words (4 wave-bytes each) of f0 (and optionally f1) equal 0x01010101
__device__ __forceinline__ void poll2(const int* f0, const int* f1) {
  const int lane = threadIdx.x & 63;
  const int* p = nullptr;
  if (lane < 32) { if (f0) p = f0 + lane; }
  else           { if (f1) p = f1 + (lane - 32); }
  for (;;) {
    int ok = 1;
    if (p) ok = (ld4_poll(p) == 0x01010101);
    if (__all(ok)) return;
  }
}

__device__ __forceinline__ float sigf(float x) { return 1.f / (1.f + __expf(-x)); }

struct B3 { f16x8 r, z, n; };
// W row-major [1536][K]; rows g*512 + j (plain cached loads — weights stay hot in L1/L2)
__device__ __forceinline__ B3 ldB(const _Float16* __restrict__ W, int K, int row0, int koff) {
  B3 o;
  const _Float16* p = W + (size_t)row0 * K + koff;
  o.r = *(const f16x8*)p;
  o.z = *(const f16x8*)(p + (size_t)512 * K);
  o.n = *(const f16x8*)(p + (size_t)1024 * K);
  return o;
}

__device__ __forceinline__ f16x8 frag(const u64* hA, int c) {
  union { u64 u[2]; f16x8 v; } x;
  x.u[0] = hA[2 * c]; x.u[1] = hA[2 * c + 1];
  return x.v;
}

__global__ void prep_x0(const int* __restrict__ texts, const float* __restrict__ emb,
                        _Float16* __restrict__ x0) {
  const size_t N = (size_t)T_STEPS * BB * EP;
  const size_t stride = (size_t)gridDim.x * blockDim.x;
  for (size_t i = (size_t)blockIdx.x * blockDim.x + threadIdx.x; i < N; i += stride) {
    int e = (int)(i % EP);
    size_t tb = i / EP;
    float v = 0.f;
    if (e < EE) v = emb[(size_t)texts[tb] * EE + e];
    x0[i] = (_Float16)v;
  }
}

__global__ void prep_w(const float* __restrict__ Wih0, const float* __restrict__ Whh0,
                       const float* __restrict__ bih0, const float* __restrict__ bhh0,
                       const float* __restrict__ Wih1, const float* __restrict__ Whh1,
                       const float* __restrict__ bih1, const float* __restrict__ bhh1,
                       _Float16* __restrict__ W0x, _Float16* __restrict__ W0h,
                       _Float16* __restrict__ W1x, _Float16* __restrict__ W1h,
                       float* __restrict__ bias0, float* __restrict__ bias1) {
  const size_t stride = (size_t)gridDim.x * blockDim.x;
  const size_t gid = (size_t)blockIdx.x * blockDim.x + threadIdx.x;
  for (size_t i = gid; i < (size_t)G3 * EP; i += stride) {
    int k = (int)(i % EP); int n = (int)(i / EP);
    W0x[i] = (k < EE) ? (_Float16)Wih0[(size_t)n * EE + k] : (_Float16)0.f;
  }
  for (size_t i = gid; i < (size_t)G3 * HH; i += stride) {
    W0h[i] = (_Float16)Whh0[i];
    W1x[i] = (_Float16)Wih1[i];
    W1h[i] = (_Float16)Whh1[i];
  }
  for (size_t i = gid; i < (size_t)HH; i += stride) {
    bias0[i]        = bih0[i] + bhh0[i];
    bias0[512 + i]  = bih0[512 + i] + bhh0[512 + i];
    bias0[1024 + i] = bih0[1024 + i];
    bias0[1536 + i] = bhh0[1024 + i];
    bias1[i]        = bih1[i] + bhh1[i];
    bias1[512 + i]  = bih1[512 + i] + bhh1[512 + i];
    bias1[1024 + i] = bih1[1024 + i];
    bias1[1536 + i] = bhh1[1024 + i];
  }
}

// 64 WGs x 256 threads. WG 0..31 = layer0 j-chunks, 32..63 = layer1 j-chunks.
// No atomic RMWs, no intra-WG barriers: each wave owns 16 batch rows end-to-end.
// flags0/flags1: one int per (step, WG); byte b = wave b's arrival. Plain stores only.
__global__ __launch_bounds__(256, 1) void gru_persistent(
    const _Float16* __restrict__ x0,
    const _Float16* __restrict__ W0x, const _Float16* __restrict__ W0h,
    const _Float16* __restrict__ W1x, const _Float16* __restrict__ W1h,
    const float* __restrict__ bias0, const float* __restrict__ bias1,
    _Float16* h1ring, _Float16* h2buf, float* pooled,
    int* flags0, int* flags1)
{
  const int wg   = blockIdx.x;
  const int L    = wg >> 5;
  const int w    = wg & 31;
  const int jb   = w * 16;
  const int tid  = threadIdx.x;
  const int bsub = tid >> 6;          // wave index: owns batch rows 16*bsub..+15
  const int lane = tid & 63;
  const int quad = lane >> 4;
  const int l15  = lane & 15;
  const int brow = bsub * 16 + l15;   // A-operand row (batch)
  const int j    = jb + l15;          // output column
  const int koff = quad * 8;

  __shared__ _Float16 tile[2][4][16][16];   // [parity][wave][row][col] — wave-private

  if (L == 0) {
    const float br = bias0[j], bz = bias0[512 + j];
    const float bnx = bias0[1024 + j], bnh = bias0[1536 + j];
    for (int s = 0; s < T_STEPS; ++s) {
      const int* f0 = (s >= 1)    ? flags0 + (size_t)(s - 1) * 32    : nullptr;
      const int* f1 = (s >= RING) ? flags1 + (size_t)(s - RING) * 32 : nullptr;  // ring throttle
      if (f0 || f1) poll2(f0, f1);

      u64 hA[32];
      if (s >= 1) {
        const _Float16* hprev = h1ring + ((s - 1) & (RING - 1)) * HB;
        const u64* hq = (const u64*)(hprev + brow * HH) + quad * 2;
        #pragma unroll
        for (int c = 0; c < 16; ++c) {          // all 32 LLC loads back-to-back: one RT
          hA[2*c]   = ld8_llc(hq + c * 8);
          hA[2*c+1] = ld8_llc(hq + c * 8 + 1);
        }
        MEMBAR();
      }

      f32x4 aR = {0.f,0.f,0.f,0.f}, aZ = {0.f,0.f,0.f,0.f};
      f32x4 aNX = {0.f,0.f,0.f,0.f}, aNH = {0.f,0.f,0.f,0.f};
      // x-part (L2-cached loads) — overlaps the LLC RT of hA
      const _Float16* xr = x0 + ((size_t)s * BB + brow) * EP;
      #pragma unroll 5
      for (int c = 0; c < 10; ++c) {
        f16x8 a = *(const f16x8*)(xr + c * 32 + koff);
        B3 bb = ldB(W0x, EP, j, c * 32 + koff);
        aR = mf(a, bb.r, aR); aZ = mf(a, bb.z, aZ); aNX = mf(a, bb.n, aNX);
      }
      if (s >= 1) {
        #pragma unroll 4
        for (int c = 0; c < 16; ++c) {
          f16x8 a = frag(hA, c);
          B3 bb = ldB(W0h, HH, j, c * 32 + koff);
          aR = mf(a, bb.r, aR); aZ = mf(a, bb.z, aZ); aNH = mf(a, bb.n, aNH);
        }
      }

      _Float16 (*tc)[16] = tile[s & 1][bsub];
      _Float16 (*tp)[16] = tile[(s + 1) & 1][bsub];
      #pragma unroll
      for (int rg = 0; rg < 4; ++rg) {
        const int rr = quad * 4 + rg;           // C/D row = quad*4+reg (within wave's 16)
        float r = sigf(aR[rg] + br);
        float z = sigf(aZ[rg] + bz);
        float n = tanhf(aNX[rg] + bnx + r * (aNH[rg] + bnh));
        float hp = (s >= 1) ? (float)tp[rr][l15] : 0.f;
        tc[rr][l15] = (_Float16)((1.f - z) * n + z * hp);
      }
      if (lane < 32) {                          // publish own 16 rows (32 x 16B stores/wave)
        const int row = lane >> 1, seg = lane & 1;
        f16x8 v = *(const f16x8*)&tc[row][seg * 8];
        st16_llc(h1ring + (s & (RING - 1)) * HB + (size_t)(bsub * 16 + row) * HH + jb + seg * 8, v);
      }
      __builtin_amdgcn_s_waitcnt(0);            // drain own stores (release)
      if (lane == 0) st1_llc((char*)(flags0 + (size_t)s * 32 + w) + bsub, 1);
    }
  } else {
    const float br = bias1[j], bz = bias1[512 + j];
    const float bnx = bias1[1024 + j], bnh = bias1[1536 + j];
    for (int t = 0; t < T_STEPS; ++t) {
      const int* f0 = flags0 + (size_t)t * 32;
      const int* f1 = (t >= 1) ? flags1 + (size_t)(t - 1) * 32 : nullptr;
      poll2(f0, f1);

      u64 A1[32], A2[32];
      {
        const _Float16* a1p = h1ring + (t & (RING - 1)) * HB;
        const u64* aq = (const u64*)(a1p + brow * HH) + quad * 2;
        #pragma unroll
        for (int c = 0; c < 16; ++c) {
          A1[2*c]   = ld8_llc(aq + c * 8);
          A1[2*c+1] = ld8_llc(aq + c * 8 + 1);
        }
      }
      if (t >= 1) {
        const _Float16* a2p = h2buf + ((t - 1) & 1) * HB;
        const u64* aq = (const u64*)(a2p + brow * HH) + quad * 2;
        #pragma unroll
        for (int c = 0; c < 16; ++c) {
          A2[2*c]   = ld8_llc(aq + c * 8);
          A2[2*c+1] = ld8_llc(aq + c * 8 + 1);
        }
      }
      MEMBAR();

      f32x4 aR = {0.f,0.f,0.f,0.f}, aZ = {0.f,0.f,0.f,0.f};
      f32x4 aNX = {0.f,0.f,0.f,0.f}, aNH = {0.f,0.f,0.f,0.f};
      #pragma unroll 4
      for (int c = 0; c < 16; ++c) {            // x-part first: overlaps A2's LLC RT
        f16x8 a = frag(A1, c);
        B3 bb = ldB(W1x, HH, j, c * 32 + koff);
        aR = mf(a, bb.r, aR); aZ = mf(a, bb.z, aZ); aNX = mf(a, bb.n, aNX);
      }
      if (t >= 1) {
        #pragma unroll 4
        for (int c = 0; c < 16; ++c) {
          f16x8 a = frag(A2, c);
          B3 bb = ldB(W1h, HH, j, c * 32 + koff);
          aR = mf(a, bb.r, aR); aZ = mf(a, bb.z, aZ); aNH = mf(a, bb.n, aNH);
        }
      }

      _Float16 (*tc)[16] = tile[t & 1][bsub];
      _Float16 (*tp)[16] = tile[(t + 1) & 1][bsub];
      #pragma unroll
      for (int rg = 0; rg < 4; ++rg) {
        const int rr = quad * 4 + rg;
        float r = sigf(aR[rg] + br);
        float z = sigf(aZ[rg] + bz);
        float n = tanhf(aNX[rg] + bnx + r * (aNH[rg] + bnh));
        float hp = (t >= 1) ? (float)tp[rr][l15] : 0.f;
        tc[rr][l15] = (_Float16)((1.f - z) * n + z * hp);
      }
      if (lane < 32) {
        const int row = lane >> 1, seg = lane & 1;
        f16x8 v = *(const f16x8*)&tc[row][seg * 8];
        st16_llc(h2buf + (t & 1) * HB + (size_t)(bsub * 16 + row) * HH + jb + seg * 8, v);
      }
      __builtin_amdgcn_s_waitcnt(0);
      if (lane == 0) st1_llc((char*)(flags1 + (size_t)t * 32 + w) + bsub, 1);
      // pooled partial (off critical path, after publish): own 16 rows -> 16 cols
      if (lane < 16) {
        float sum = 0.f;
        #pragma unroll
        for (int r = 0; r < 16; ++r) sum += (float)tc[r][lane];
        atomicAdd(pooled + (size_t)t * HH + jb + lane, sum);   // raw sum over b; /64 in FC
      }
    }
  }
}

__global__ void fc_kernel(const float* __restrict__ pooled, const float* __restrict__ fcW,
                          const float* __restrict__ fcb, float* __restrict__ out) {
  const int t = blockIdx.x;
  const int lane = threadIdx.x;  // 64 = one wave
  float a0 = 0.f, a1 = 0.f, a2 = 0.f, a3 = 0.f, a4 = 0.f;
  for (int jj = lane; jj < HH; jj += 64) {
    float p = pooled[(size_t)t * HH + jj];
    a0 += p * fcW[jj];
    a1 += p * fcW[512 + jj];
    a2 += p * fcW[1024 + jj];
    a3 += p * fcW[1536 + jj];
    a4 += p * fcW[2048 + jj];
  }
  #pragma unroll
  for (int off = 32; off > 0; off >>= 1) {
    a0 += __shfl_down(a0, off, 64);
    a1 += __shfl_down(a1, off, 64);
    a2 += __shfl_down(a2, off, 64);
    a3 += __shfl_down(a3, off, 64);
    a4 += __shfl_down(a4, off, 64);
  }
  if (lane == 0) {
    const float sc = 1.f / 64.f;
    out[t * 5 + 0] = a0 * sc + fcb[0];
    out[t * 5 + 1] = a1 * sc + fcb[1];
    out[t * 5 + 2] = a2 * sc + fcb[2];
    out[t * 5 + 3] = a3 * sc + fcb[3];
    out[t * 5 + 4] = a4 * sc + fcb[4];
  }
}

extern "C" void kernel_launch(void* const* d_in, const int* in_sizes, int n_in,
                              void* d_out, int out_size, void* d_ws, size_t ws_size,
                              hipStream_t stream) {
  const int*   texts = (const int*)  d_in[0];
  const float* emb   = (const float*)d_in[1];
  const float* Wih0  = (const float*)d_in[2];
  const float* Whh0  = (const float*)d_in[3];
  const float* bih0  = (const float*)d_in[4];
  const float* bhh0  = (const float*)d_in[5];
  const float* Wih1  = (const float*)d_in[6];
  const float* Whh1  = (const float*)d_in[7];
  const float* bih1  = (const float*)d_in[8];
  const float* bhh1  = (const float*)d_in[9];
  const float* fcW   = (const float*)d_in[10];
  const float* fcb   = (const float*)d_in[11];
  float* out = (float*)d_out;

  char* ws = (char*)d_ws;
  int*      flags0 = (int*)ws;                        // 65536 B  [512][32] int
  int*      flags1 = (int*)(ws + 65536);              // 65536 B
  float*    pooled = (float*)(ws + 131072);           // 1048576 B [512][512] f32
  _Float16* h1ring = (_Float16*)(ws + 1179648);       // 262144 B (4 x 64x512 f16)
  _Float16* h2buf  = (_Float16*)(ws + 1441792);       // 131072 B (2 slots)
  _Float16* x0     = (_Float16*)(ws + 1572864);       // 20971520 B [512][64][320]
  _Float16* W0x    = (_Float16*)(ws + 22544384);      // 983040 B  [1536][320]
  _Float16* W0h    = (_Float16*)(ws + 23527424);      // 1572864 B [1536][512]
  _Float16* W1x    = (_Float16*)(ws + 25100288);      // 1572864 B
  _Float16* W1h    = (_Float16*)(ws + 26673152);      // 1572864 B
  float*    bias0  = (float*)(ws + 28246016);         // 8192 B (r,z,nx,nh)
  float*    bias1  = (float*)(ws + 28254208);         // 8192 B
  // total ws use: 28262400 B

  hipMemsetAsync(ws, 0, 1179648, stream);  // flags0 + flags1 + pooled = zeros
  prep_x0<<<4096, 256, 0, stream>>>(texts, emb, x0);
  prep_w<<<1024, 256, 0, stream>>>(Wih0, Whh0, bih0, bhh0, Wih1, Whh1, bih1, bhh1,
                                   W0x, W0h, W1x, W1h, bias0, bias1);
  gru_persistent<<<64, 256, 0, stream>>>(x0, W0x, W0h, W1x, W1h, bias0, bias1,
                                         h1ring, h2buf, pooled, flags0, flags1);
  fc_kernel<<<512, 64, 0, stream>>>(pooled, fcW, fcb, out);
}

// Round 5
// 13890.683 us; speedup vs baseline: 1.1443x; 1.1443x over previous
//
#include <hip/hip_runtime.h>

#define T_STEPS 512
#define BB 64
#define EE 300
#define EP 320
#define HH 512
#define G3 1536
#define HB (BB*HH)   // halves per h slot
#define RING 4

typedef _Float16 f16x8 __attribute__((ext_vector_type(8)));
typedef float f32x4 __attribute__((ext_vector_type(4)));
typedef int i32x4 __attribute__((ext_vector_type(4)));

__device__ __forceinline__ f32x4 mf(f16x8 a, f16x8 b, f32x4 c) {
  return __builtin_amdgcn_mfma_f32_16x16x32_f16(a, b, c, 0, 0, 0);
}

struct HMat { i32x4 q[16]; };   // 64 VGPRs: one lane's 16 fragments of a 64x512 f16 matrix

// 16 back-to-back LLC(sc1) 16B loads + FULL drain, all inside ONE asm block.
// No in-flight register ever escapes the block (round-4 NaN was RA copying
// in-flight regs between split blocks). voff = brow*1024 + quad*16.
#define LOADS16_W0                                                   \
    "global_load_dwordx4 %0,  %16, %17 sc1\n\t"                      \
    "global_load_dwordx4 %1,  %16, %17 offset:64 sc1\n\t"            \
    "global_load_dwordx4 %2,  %16, %17 offset:128 sc1\n\t"           \
    "global_load_dwordx4 %3,  %16, %17 offset:192 sc1\n\t"           \
    "global_load_dwordx4 %4,  %16, %17 offset:256 sc1\n\t"           \
    "global_load_dwordx4 %5,  %16, %17 offset:320 sc1\n\t"           \
    "global_load_dwordx4 %6,  %16, %17 offset:384 sc1\n\t"           \
    "global_load_dwordx4 %7,  %16, %17 offset:448 sc1\n\t"           \
    "global_load_dwordx4 %8,  %16, %17 offset:512 sc1\n\t"           \
    "global_load_dwordx4 %9,  %16, %17 offset:576 sc1\n\t"           \
    "global_load_dwordx4 %10, %16, %17 offset:640 sc1\n\t"           \
    "global_load_dwordx4 %11, %16, %17 offset:704 sc1\n\t"           \
    "global_load_dwordx4 %12, %16, %17 offset:768 sc1\n\t"           \
    "global_load_dwordx4 %13, %16, %17 offset:832 sc1\n\t"           \
    "global_load_dwordx4 %14, %16, %17 offset:896 sc1\n\t"           \
    "global_load_dwordx4 %15, %16, %17 offset:960 sc1\n\t"           \
    "s_waitcnt vmcnt(0)"

#define HM_OUTS(m) "=v"((m).q[0]), "=v"((m).q[1]), "=v"((m).q[2]), "=v"((m).q[3]),   \
                   "=v"((m).q[4]), "=v"((m).q[5]), "=v"((m).q[6]), "=v"((m).q[7]),   \
                   "=v"((m).q[8]), "=v"((m).q[9]), "=v"((m).q[10]), "=v"((m).q[11]), \
                   "=v"((m).q[12]), "=v"((m).q[13]), "=v"((m).q[14]), "=v"((m).q[15])

__device__ __forceinline__ void load16_wait0(HMat& m, const void* base, int voff) {
  asm volatile(LOADS16_W0 : HM_OUTS(m) : "v"(voff), "s"(base) : "memory");
}

// batched x-prefetch: 10 plain cached 16B loads + full drain (single block, safe)
__device__ __forceinline__ void loadx10_wait(i32x4* xq, const void* base, int voff) {
  asm volatile(
    "global_load_dwordx4 %0, %10, %11\n\t"
    "global_load_dwordx4 %1, %10, %11 offset:64\n\t"
    "global_load_dwordx4 %2, %10, %11 offset:128\n\t"
    "global_load_dwordx4 %3, %10, %11 offset:192\n\t"
    "global_load_dwordx4 %4, %10, %11 offset:256\n\t"
    "global_load_dwordx4 %5, %10, %11 offset:320\n\t"
    "global_load_dwordx4 %6, %10, %11 offset:384\n\t"
    "global_load_dwordx4 %7, %10, %11 offset:448\n\t"
    "global_load_dwordx4 %8, %10, %11 offset:512\n\t"
    "global_load_dwordx4 %9, %10, %11 offset:576\n\t"
    "s_waitcnt vmcnt(0)"
    : "=v"(xq[0]), "=v"(xq[1]), "=v"(xq[2]), "=v"(xq[3]), "=v"(xq[4]),
      "=v"(xq[5]), "=v"(xq[6]), "=v"(xq[7]), "=v"(xq[8]), "=v"(xq[9])
    : "v"(voff), "s"(base) : "memory");
}

__device__ __forceinline__ f16x8 fragq(i32x4 q) {
  union { i32x4 i; f16x8 v; } x; x.i = q; return x.v;
}

// LLC-coherent 16B store (coalesced)
__device__ __forceinline__ void st16_llc(void* p, f16x8 v) {
  i32x4 iv;
  __builtin_memcpy(&iv, &v, 16);
  asm volatile("global_store_dwordx4 %0, %1, off sc0 sc1" :: "v"(p), "v"(iv) : "memory");
}

// flag publish: plain byte store at LLC (no RMW)
__device__ __forceinline__ void st1_llc(char* p, int v) {
  asm volatile("global_store_byte %0, %1, off sc0 sc1" :: "v"(p), "v"(v) : "memory");
}

// fresh 4B poll load from LLC
__device__ __forceinline__ int ld4_poll(const int* p) {
  int r;
  asm volatile("global_load_dword %0, %1, off sc1\n\ts_waitcnt vmcnt(0)"
               : "=v"(r) : "v"(p) : "memory");
  return r;
}

// wait until all 32 WG-words (4 wave-bytes each) of f0 (and optionally f1) equal 0x01010101
__device__ __forceinline__ void poll2(const int* f0, const int* f1) {
  const int lane = threadIdx.x & 63;
  const int* p = nullptr;
  if (lane < 32) { if (f0) p = f0 + lane; }
  else           { if (f1) p = f1 + (lane - 32); }
  for (;;) {
    int ok = 1;
    if (p) ok = (ld4_poll(p) == 0x01010101);
    if (__all(ok)) return;
  }
}

__device__ __forceinline__ float sigf(float x) { return 1.f / (1.f + __expf(-x)); }

struct B3 { f16x8 r, z, n; };
// W row-major [1536][K]; rows g*512 + j (plain cached loads — weights stay hot in L1/L2)
__device__ __forceinline__ B3 ldB(const _Float16* __restrict__ W, int K, int row0, int koff) {
  B3 o;
  const _Float16* p = W + (size_t)row0 * K + koff;
  o.r = *(const f16x8*)p;
  o.z = *(const f16x8*)(p + (size_t)512 * K);
  o.n = *(const f16x8*)(p + (size_t)1024 * K);
  return o;
}

__global__ void prep_x0(const int* __restrict__ texts, const float* __restrict__ emb,
                        _Float16* __restrict__ x0) {
  const size_t N = (size_t)T_STEPS * BB * EP;
  const size_t stride = (size_t)gridDim.x * blockDim.x;
  for (size_t i = (size_t)blockIdx.x * blockDim.x + threadIdx.x; i < N; i += stride) {
    int e = (int)(i % EP);
    size_t tb = i / EP;
    float v = 0.f;
    if (e < EE) v = emb[(size_t)texts[tb] * EE + e];
    x0[i] = (_Float16)v;
  }
}

__global__ void prep_w(const float* __restrict__ Wih0, const float* __restrict__ Whh0,
                       const float* __restrict__ bih0, const float* __restrict__ bhh0,
                       const float* __restrict__ Wih1, const float* __restrict__ Whh1,
                       const float* __restrict__ bih1, const float* __restrict__ bhh1,
                       _Float16* __restrict__ W0x, _Float16* __restrict__ W0h,
                       _Float16* __restrict__ W1x, _Float16* __restrict__ W1h,
                       float* __restrict__ bias0, float* __restrict__ bias1) {
  const size_t stride = (size_t)gridDim.x * blockDim.x;
  const size_t gid = (size_t)blockIdx.x * blockDim.x + threadIdx.x;
  for (size_t i = gid; i < (size_t)G3 * EP; i += stride) {
    int k = (int)(i % EP); int n = (int)(i / EP);
    W0x[i] = (k < EE) ? (_Float16)Wih0[(size_t)n * EE + k] : (_Float16)0.f;
  }
  for (size_t i = gid; i < (size_t)G3 * HH; i += stride) {
    W0h[i] = (_Float16)Whh0[i];
    W1x[i] = (_Float16)Wih1[i];
    W1h[i] = (_Float16)Whh1[i];
  }
  for (size_t i = gid; i < (size_t)HH; i += stride) {
    bias0[i]        = bih0[i] + bhh0[i];
    bias0[512 + i]  = bih0[512 + i] + bhh0[512 + i];
    bias0[1024 + i] = bih0[1024 + i];
    bias0[1536 + i] = bhh0[1024 + i];
    bias1[i]        = bih1[i] + bhh1[i];
    bias1[512 + i]  = bih1[512 + i] + bhh1[512 + i];
    bias1[1024 + i] = bih1[1024 + i];
    bias1[1536 + i] = bhh1[1024 + i];
  }
}

// 64 WGs x 256 threads. WG 0..31 = layer0 j-chunks, 32..63 = layer1 j-chunks.
// No RMWs, no intra-WG barriers; h loads are single-block asm-batched:
// 1 LLC RT per h-matrix instead of ~16 serialized RTs.
__global__ __launch_bounds__(256, 1) void gru_persistent(
    const _Float16* __restrict__ x0,
    const _Float16* __restrict__ W0x, const _Float16* __restrict__ W0h,
    const _Float16* __restrict__ W1x, const _Float16* __restrict__ W1h,
    const float* __restrict__ bias0, const float* __restrict__ bias1,
    _Float16* h1ring, _Float16* h2buf, float* pooled,
    int* flags0, int* flags1)
{
  const int wg   = blockIdx.x;
  const int L    = wg >> 5;
  const int w    = wg & 31;
  const int jb   = w * 16;
  const int tid  = threadIdx.x;
  const int bsub = tid >> 6;          // wave index: owns batch rows 16*bsub..+15
  const int lane = tid & 63;
  const int quad = lane >> 4;
  const int l15  = lane & 15;
  const int brow = bsub * 16 + l15;   // A-operand row (batch)
  const int j    = jb + l15;          // output column
  const int koff = quad * 8;
  const int hoff = brow * (HH * 2) + quad * 16;   // byte voffset into an h slot

  __shared__ _Float16 tile[2][4][16][16];   // [parity][wave][row][col] — wave-private

  if (L == 0) {
    const float br = bias0[j], bz = bias0[512 + j];
    const float bnx = bias0[1024 + j], bnh = bias0[1536 + j];
    const int xoff = brow * (EP * 2) + quad * 16;
    i32x4 xq[10];
    loadx10_wait(xq, x0, xoff);       // stage-0 x
    for (int s = 0; s < T_STEPS; ++s) {
      const int* f0 = (s >= 1)    ? flags0 + (size_t)(s - 1) * 32    : nullptr;
      const int* f1 = (s >= RING) ? flags1 + (size_t)(s - RING) * 32 : nullptr;  // ring throttle
      if (f0 || f1) poll2(f0, f1);

      HMat hA;
      if (s >= 1)                      // 16 batched loads, 1 LLC RT, drained in-block
        load16_wait0(hA, h1ring + ((s - 1) & (RING - 1)) * HB, hoff);

      f32x4 aR = {0.f,0.f,0.f,0.f}, aZ = {0.f,0.f,0.f,0.f};
      f32x4 aNX = {0.f,0.f,0.f,0.f}, aNH = {0.f,0.f,0.f,0.f};
      #pragma unroll 5
      for (int c = 0; c < 10; ++c) {   // x-part on prefetched regs
        f16x8 a = fragq(xq[c]);
        B3 bb = ldB(W0x, EP, j, c * 32 + koff);
        aR = mf(a, bb.r, aR); aZ = mf(a, bb.z, aZ); aNX = mf(a, bb.n, aNX);
      }
      if (s >= 1) {
        #pragma unroll 4
        for (int c = 0; c < 16; ++c) {
          f16x8 a = fragq(hA.q[c]);
          B3 bb = ldB(W0h, HH, j, c * 32 + koff);
          aR = mf(a, bb.r, aR); aZ = mf(a, bb.z, aZ); aNH = mf(a, bb.n, aNH);
        }
      }

      _Float16 (*tc)[16] = tile[s & 1][bsub];
      _Float16 (*tp)[16] = tile[(s + 1) & 1][bsub];
      #pragma unroll
      for (int rg = 0; rg < 4; ++rg) {
        const int rr = quad * 4 + rg;           // C/D row = quad*4+reg (within wave's 16)
        float r = sigf(aR[rg] + br);
        float z = sigf(aZ[rg] + bz);
        float n = tanhf(aNX[rg] + bnx + r * (aNH[rg] + bnh));
        float hp = (s >= 1) ? (float)tp[rr][l15] : 0.f;
        tc[rr][l15] = (_Float16)((1.f - z) * n + z * hp);
      }
      if (lane < 32) {                          // publish own 16 rows
        const int row = lane >> 1, seg = lane & 1;
        f16x8 v = *(const f16x8*)&tc[row][seg * 8];
        st16_llc(h1ring + (s & (RING - 1)) * HB + (size_t)(bsub * 16 + row) * HH + jb + seg * 8, v);
      }
      __builtin_amdgcn_s_waitcnt(0);            // drain own stores (release)
      if (lane == 0) st1_llc((char*)(flags0 + (size_t)s * 32 + w) + bsub, 1);
      if (s + 1 < T_STEPS)                      // batched x prefetch, off critical path
        loadx10_wait(xq, x0 + (size_t)(s + 1) * BB * EP, xoff);
    }
  } else {
    const float br = bias1[j], bz = bias1[512 + j];
    const float bnx = bias1[1024 + j], bnh = bias1[1536 + j];
    for (int t = 0; t < T_STEPS; ++t) {
      const int* f0 = flags0 + (size_t)t * 32;
      const int* f1 = (t >= 1) ? flags1 + (size_t)(t - 1) * 32 : nullptr;
      poll2(f0, f1);

      HMat A1;
      load16_wait0(A1, h1ring + (t & (RING - 1)) * HB, hoff);

      f32x4 aR = {0.f,0.f,0.f,0.f}, aZ = {0.f,0.f,0.f,0.f};
      f32x4 aNX = {0.f,0.f,0.f,0.f}, aNH = {0.f,0.f,0.f,0.f};
      #pragma unroll 4
      for (int c = 0; c < 16; ++c) {            // x-part (A1)
        f16x8 a = fragq(A1.q[c]);
        B3 bb = ldB(W1x, HH, j, c * 32 + koff);
        aR = mf(a, bb.r, aR); aZ = mf(a, bb.z, aZ); aNX = mf(a, bb.n, aNX);
      }
      if (t >= 1) {
        HMat A2;
        load16_wait0(A2, h2buf + ((t - 1) & 1) * HB, hoff);
        #pragma unroll 4
        for (int c = 0; c < 16; ++c) {
          f16x8 a = fragq(A2.q[c]);
          B3 bb = ldB(W1h, HH, j, c * 32 + koff);
          aR = mf(a, bb.r, aR); aZ = mf(a, bb.z, aZ); aNH = mf(a, bb.n, aNH);
        }
      }

      _Float16 (*tc)[16] = tile[t & 1][bsub];
      _Float16 (*tp)[16] = tile[(t + 1) & 1][bsub];
      #pragma unroll
      for (int rg = 0; rg < 4; ++rg) {
        const int rr = quad * 4 + rg;
        float r = sigf(aR[rg] + br);
        float z = sigf(aZ[rg] + bz);
        float n = tanhf(aNX[rg] + bnx + r * (aNH[rg] + bnh));
        float hp = (t >= 1) ? (float)tp[rr][l15] : 0.f;
        tc[rr][l15] = (_Float16)((1.f - z) * n + z * hp);
      }
      if (lane < 32) {
        const int row = lane >> 1, seg = lane & 1;
        f16x8 v = *(const f16x8*)&tc[row][seg * 8];
        st16_llc(h2buf + (t & 1) * HB + (size_t)(bsub * 16 + row) * HH + jb + seg * 8, v);
      }
      __builtin_amdgcn_s_waitcnt(0);
      if (lane == 0) st1_llc((char*)(flags1 + (size_t)t * 32 + w) + bsub, 1);
      // pooled partial (off critical path, after publish): own 16 rows -> 16 cols
      if (lane < 16) {
        float sum = 0.f;
        #pragma unroll
        for (int r = 0; r < 16; ++r) sum += (float)tc[r][lane];
        atomicAdd(pooled + (size_t)t * HH + jb + lane, sum);   // raw sum over b; /64 in FC
      }
    }
  }
}

__global__ void fc_kernel(const float* __restrict__ pooled, const float* __restrict__ fcW,
                          const float* __restrict__ fcb, float* __restrict__ out) {
  const int t = blockIdx.x;
  const int lane = threadIdx.x;  // 64 = one wave
  float a0 = 0.f, a1 = 0.f, a2 = 0.f, a3 = 0.f, a4 = 0.f;
  for (int jj = lane; jj < HH; jj += 64) {
    float p = pooled[(size_t)t * HH + jj];
    a0 += p * fcW[jj];
    a1 += p * fcW[512 + jj];
    a2 += p * fcW[1024 + jj];
    a3 += p * fcW[1536 + jj];
    a4 += p * fcW[2048 + jj];
  }
  #pragma unroll
  for (int off = 32; off > 0; off >>= 1) {
    a0 += __shfl_down(a0, off, 64);
    a1 += __shfl_down(a1, off, 64);
    a2 += __shfl_down(a2, off, 64);
    a3 += __shfl_down(a3, off, 64);
    a4 += __shfl_down(a4, off, 64);
  }
  if (lane == 0) {
    const float sc = 1.f / 64.f;
    out[t * 5 + 0] = a0 * sc + fcb[0];
    out[t * 5 + 1] = a1 * sc + fcb[1];
    out[t * 5 + 2] = a2 * sc + fcb[2];
    out[t * 5 + 3] = a3 * sc + fcb[3];
    out[t * 5 + 4] = a4 * sc + fcb[4];
  }
}

extern "C" void kernel_launch(void* const* d_in, const int* in_sizes, int n_in,
                              void* d_out, int out_size, void* d_ws, size_t ws_size,
                              hipStream_t stream) {
  const int*   texts = (const int*)  d_in[0];
  const float* emb   = (const float*)d_in[1];
  const float* Wih0  = (const float*)d_in[2];
  const float* Whh0  = (const float*)d_in[3];
  const float* bih0  = (const float*)d_in[4];
  const float* bhh0  = (const float*)d_in[5];
  const float* Wih1  = (const float*)d_in[6];
  const float* Whh1  = (const float*)d_in[7];
  const float* bih1  = (const float*)d_in[8];
  const float* bhh1  = (const float*)d_in[9];
  const float* fcW   = (const float*)d_in[10];
  const float* fcb   = (const float*)d_in[11];
  float* out = (float*)d_out;

  char* ws = (char*)d_ws;
  int*      flags0 = (int*)ws;                        // 65536 B  [512][32] int
  int*      flags1 = (int*)(ws + 65536);              // 65536 B
  float*    pooled = (float*)(ws + 131072);           // 1048576 B [512][512] f32
  _Float16* h1ring = (_Float16*)(ws + 1179648);       // 262144 B (4 x 64x512 f16)
  _Float16* h2buf  = (_Float16*)(ws + 1441792);       // 131072 B (2 slots)
  _Float16* x0     = (_Float16*)(ws + 1572864);       // 20971520 B [512][64][320]
  _Float16* W0x    = (_Float16*)(ws + 22544384);      // 983040 B  [1536][320]
  _Float16* W0h    = (_Float16*)(ws + 23527424);      // 1572864 B [1536][512]
  _Float16* W1x    = (_Float16*)(ws + 25100288);      // 1572864 B
  _Float16* W1h    = (_Float16*)(ws + 26673152);      // 1572864 B
  float*    bias0  = (float*)(ws + 28246016);         // 8192 B (r,z,nx,nh)
  float*    bias1  = (float*)(ws + 28254208);         // 8192 B
  // total ws use: 28262400 B

  hipMemsetAsync(ws, 0, 1179648, stream);  // flags0 + flags1 + pooled = zeros
  prep_x0<<<4096, 256, 0, stream>>>(texts, emb, x0);
  prep_w<<<1024, 256, 0, stream>>>(Wih0, Whh0, bih0, bhh0, Wih1, Whh1, bih1, bhh1,
                                   W0x, W0h, W1x, W1h, bias0, bias1);
  gru_persistent<<<64, 256, 0, stream>>>(x0, W0x, W0h, W1x, W1h, bias0, bias1,
                                         h1ring, h2buf, pooled, flags0, flags1);
  fc_kernel<<<512, 64, 0, stream>>>(pooled, fcW, fcb, out);
}

// Round 6
// 12940.131 us; speedup vs baseline: 1.2283x; 1.0735x over previous
//
#include <hip/hip_runtime.h>

#define T_STEPS 512
#define BB 64
#define EE 300
#define EP 320
#define HH 512
#define G3 1536
#define HB (BB*HH)   // halves per h slot
#define RING 4

typedef _Float16 f16x8 __attribute__((ext_vector_type(8)));
typedef float f32x4 __attribute__((ext_vector_type(4)));
typedef int i32x4 __attribute__((ext_vector_type(4)));

__device__ __forceinline__ f32x4 mf(f16x8 a, f16x8 b, f32x4 c) {
  return __builtin_amdgcn_mfma_f32_16x16x32_f16(a, b, c, 0, 0, 0);
}

struct HMat { i32x4 q[16]; };   // 64 VGPRs: one lane's 16 fragments of a 64x512 f16 matrix

// 16 back-to-back LLC(sc1) 16B loads + FULL drain, all inside ONE asm block
// (in-flight regs must never escape an asm block — round-4 NaN lesson).
#define LOADS16_W0                                                   \
    "global_load_dwordx4 %0,  %16, %17 sc1\n\t"                      \
    "global_load_dwordx4 %1,  %16, %17 offset:64 sc1\n\t"            \
    "global_load_dwordx4 %2,  %16, %17 offset:128 sc1\n\t"           \
    "global_load_dwordx4 %3,  %16, %17 offset:192 sc1\n\t"           \
    "global_load_dwordx4 %4,  %16, %17 offset:256 sc1\n\t"           \
    "global_load_dwordx4 %5,  %16, %17 offset:320 sc1\n\t"           \
    "global_load_dwordx4 %6,  %16, %17 offset:384 sc1\n\t"           \
    "global_load_dwordx4 %7,  %16, %17 offset:448 sc1\n\t"           \
    "global_load_dwordx4 %8,  %16, %17 offset:512 sc1\n\t"           \
    "global_load_dwordx4 %9,  %16, %17 offset:576 sc1\n\t"           \
    "global_load_dwordx4 %10, %16, %17 offset:640 sc1\n\t"           \
    "global_load_dwordx4 %11, %16, %17 offset:704 sc1\n\t"           \
    "global_load_dwordx4 %12, %16, %17 offset:768 sc1\n\t"           \
    "global_load_dwordx4 %13, %16, %17 offset:832 sc1\n\t"           \
    "global_load_dwordx4 %14, %16, %17 offset:896 sc1\n\t"           \
    "global_load_dwordx4 %15, %16, %17 offset:960 sc1\n\t"           \
    "s_waitcnt vmcnt(0)"

#define HM_OUTS(m) "=v"((m).q[0]), "=v"((m).q[1]), "=v"((m).q[2]), "=v"((m).q[3]),   \
                   "=v"((m).q[4]), "=v"((m).q[5]), "=v"((m).q[6]), "=v"((m).q[7]),   \
                   "=v"((m).q[8]), "=v"((m).q[9]), "=v"((m).q[10]), "=v"((m).q[11]), \
                   "=v"((m).q[12]), "=v"((m).q[13]), "=v"((m).q[14]), "=v"((m).q[15])

__device__ __forceinline__ void load16_wait0(HMat& m, const void* base, int voff) {
  asm volatile(LOADS16_W0 : HM_OUTS(m) : "v"(voff), "s"(base) : "memory");
}

// batched x-prefetch: 10 plain cached 16B loads + full drain (single block, safe)
__device__ __forceinline__ void loadx10_wait(i32x4* xq, const void* base, int voff) {
  asm volatile(
    "global_load_dwordx4 %0, %10, %11\n\t"
    "global_load_dwordx4 %1, %10, %11 offset:64\n\t"
    "global_load_dwordx4 %2, %10, %11 offset:128\n\t"
    "global_load_dwordx4 %3, %10, %11 offset:192\n\t"
    "global_load_dwordx4 %4, %10, %11 offset:256\n\t"
    "global_load_dwordx4 %5, %10, %11 offset:320\n\t"
    "global_load_dwordx4 %6, %10, %11 offset:384\n\t"
    "global_load_dwordx4 %7, %10, %11 offset:448\n\t"
    "global_load_dwordx4 %8, %10, %11 offset:512\n\t"
    "global_load_dwordx4 %9, %10, %11 offset:576\n\t"
    "s_waitcnt vmcnt(0)"
    : "=v"(xq[0]), "=v"(xq[1]), "=v"(xq[2]), "=v"(xq[3]), "=v"(xq[4]),
      "=v"(xq[5]), "=v"(xq[6]), "=v"(xq[7]), "=v"(xq[8]), "=v"(xq[9])
    : "v"(voff), "s"(base) : "memory");
}

__device__ __forceinline__ f16x8 fragq(i32x4 q) {
  union { i32x4 i; f16x8 v; } x; x.i = q; return x.v;
}

// LLC-coherent 16B store (coalesced)
__device__ __forceinline__ void st16_llc(void* p, f16x8 v) {
  i32x4 iv;
  __builtin_memcpy(&iv, &v, 16);
  asm volatile("global_store_dwordx4 %0, %1, off sc0 sc1" :: "v"(p), "v"(iv) : "memory");
}

// flag publish: plain byte store at LLC (no RMW)
__device__ __forceinline__ void st1_llc(char* p, int v) {
  asm volatile("global_store_byte %0, %1, off sc0 sc1" :: "v"(p), "v"(v) : "memory");
}

// 4B word store at LLC (aggregator broadcast)
__device__ __forceinline__ void st4_llc(int* p, int v) {
  asm volatile("global_store_dword %0, %1, off sc0 sc1" :: "v"(p), "v"(v) : "memory");
}

// fresh 4B poll load from LLC
__device__ __forceinline__ int ld4_poll(const int* p) {
  int r;
  asm volatile("global_load_dword %0, %1, off sc1\n\ts_waitcnt vmcnt(0)"
               : "=v"(r) : "v"(p) : "memory");
  return r;
}

// Consumer wait: ONLY wave 0 polls; lane 0 polls this WG's private go0 line,
// lane 1 its go1 line (single-reader single-writer lines -> no poll storm).
// Other waves are released by the barrier.
__device__ __forceinline__ void wg_wait(const int* g0, int tgt0, const int* g1, int tgt1) {
  if ((threadIdx.x >> 6) == 0) {
    const int lane = threadIdx.x & 63;
    const int* p = nullptr; int tgt = 0;
    if (lane == 0 && g0) { p = g0; tgt = tgt0; }
    if (lane == 1 && g1) { p = g1; tgt = tgt1; }
    for (;;) {
      int ok = 1;
      if (p) ok = (ld4_poll(p) >= tgt);
      if (__all(ok)) break;
      __builtin_amdgcn_s_sleep(1);
    }
  }
  __syncthreads();
}

__device__ __forceinline__ float sigf(float x) { return 1.f / (1.f + __expf(-x)); }

struct B3 { f16x8 r, z, n; };
// W row-major [1536][K]; rows g*512 + j (plain cached loads — weights stay hot in L1/L2)
__device__ __forceinline__ B3 ldB(const _Float16* __restrict__ W, int K, int row0, int koff) {
  B3 o;
  const _Float16* p = W + (size_t)row0 * K + koff;
  o.r = *(const f16x8*)p;
  o.z = *(const f16x8*)(p + (size_t)512 * K);
  o.n = *(const f16x8*)(p + (size_t)1024 * K);
  return o;
}

__global__ void prep_x0(const int* __restrict__ texts, const float* __restrict__ emb,
                        _Float16* __restrict__ x0) {
  const size_t N = (size_t)T_STEPS * BB * EP;
  const size_t stride = (size_t)gridDim.x * blockDim.x;
  for (size_t i = (size_t)blockIdx.x * blockDim.x + threadIdx.x; i < N; i += stride) {
    int e = (int)(i % EP);
    size_t tb = i / EP;
    float v = 0.f;
    if (e < EE) v = emb[(size_t)texts[tb] * EE + e];
    x0[i] = (_Float16)v;
  }
}

__global__ void prep_w(const float* __restrict__ Wih0, const float* __restrict__ Whh0,
                       const float* __restrict__ bih0, const float* __restrict__ bhh0,
                       const float* __restrict__ Wih1, const float* __restrict__ Whh1,
                       const float* __restrict__ bih1, const float* __restrict__ bhh1,
                       _Float16* __restrict__ W0x, _Float16* __restrict__ W0h,
                       _Float16* __restrict__ W1x, _Float16* __restrict__ W1h,
                       float* __restrict__ bias0, float* __restrict__ bias1) {
  const size_t stride = (size_t)gridDim.x * blockDim.x;
  const size_t gid = (size_t)blockIdx.x * blockDim.x + threadIdx.x;
  for (size_t i = gid; i < (size_t)G3 * EP; i += stride) {
    int k = (int)(i % EP); int n = (int)(i / EP);
    W0x[i] = (k < EE) ? (_Float16)Wih0[(size_t)n * EE + k] : (_Float16)0.f;
  }
  for (size_t i = gid; i < (size_t)G3 * HH; i += stride) {
    W0h[i] = (_Float16)Whh0[i];
    W1x[i] = (_Float16)Wih1[i];
    W1h[i] = (_Float16)Whh1[i];
  }
  for (size_t i = gid; i < (size_t)HH; i += stride) {
    bias0[i]        = bih0[i] + bhh0[i];
    bias0[512 + i]  = bih0[512 + i] + bhh0[512 + i];
    bias0[1024 + i] = bih0[1024 + i];
    bias0[1536 + i] = bhh0[1024 + i];
    bias1[i]        = bih1[i] + bhh1[i];
    bias1[512 + i]  = bih1[512 + i] + bhh1[512 + i];
    bias1[1024 + i] = bih1[1024 + i];
    bias1[1536 + i] = bhh1[1024 + i];
  }
}

// 65 WGs x 256 threads. WG 0..31 = layer0 j-chunks, 32..63 = layer1 j-chunks,
// WG 64 = aggregator (sole poller of producer flags; broadcasts monotonic
// step counters to per-WG private go-lines).
__global__ __launch_bounds__(256, 1) void gru_persistent(
    const _Float16* __restrict__ x0,
    const _Float16* __restrict__ W0x, const _Float16* __restrict__ W0h,
    const _Float16* __restrict__ W1x, const _Float16* __restrict__ W1h,
    const float* __restrict__ bias0, const float* __restrict__ bias1,
    _Float16* h1ring, _Float16* h2buf, float* pooled,
    int* flags0, int* flags1, int* go0, int* go1)
{
  const int wg   = blockIdx.x;
  const int tid  = threadIdx.x;

  if (wg == 64) {   // ---- aggregator ----
    const int wave = tid >> 6, lane = tid & 63;
    if (wave == 0) {
      for (int s = 0; s < T_STEPS; ++s) {
        const int* f = flags0 + (size_t)s * 32;
        for (;;) {
          int ok = 1;
          if (lane < 32) ok = (ld4_poll(f + lane) == 0x01010101);
          if (__all(ok)) break;
        }
        st4_llc(go0 + lane * 16, s + 1);   // 64 private lines (64B apart)
      }
    } else if (wave == 1) {
      for (int t = 0; t < T_STEPS; ++t) {
        const int* f = flags1 + (size_t)t * 32;
        for (;;) {
          int ok = 1;
          if (lane < 32) ok = (ld4_poll(f + lane) == 0x01010101);
          if (__all(ok)) break;
        }
        st4_llc(go1 + lane * 16, t + 1);
      }
    }
    return;
  }

  const int L    = wg >> 5;
  const int w    = wg & 31;
  const int jb   = w * 16;
  const int bsub = tid >> 6;          // wave index: owns batch rows 16*bsub..+15
  const int lane = tid & 63;
  const int quad = lane >> 4;
  const int l15  = lane & 15;
  const int brow = bsub * 16 + l15;   // A-operand row (batch)
  const int j    = jb + l15;          // output column
  const int koff = quad * 8;
  const int hoff = brow * (HH * 2) + quad * 16;   // byte voffset into an h slot
  const int* g0p = go0 + wg * 16;     // this WG's private go lines
  const int* g1p = go1 + wg * 16;

  __shared__ _Float16 tile[2][4][16][16];   // [parity][wave][row][col] — wave-private

  if (L == 0) {
    const float br = bias0[j], bz = bias0[512 + j];
    const float bnx = bias0[1024 + j], bnh = bias0[1536 + j];
    const int xoff = brow * (EP * 2) + quad * 16;
    i32x4 xq[10];
    loadx10_wait(xq, x0, xoff);       // stage-0 x
    for (int s = 0; s < T_STEPS; ++s) {
      f32x4 aR = {0.f,0.f,0.f,0.f}, aZ = {0.f,0.f,0.f,0.f};
      f32x4 aNX = {0.f,0.f,0.f,0.f}, aNH = {0.f,0.f,0.f,0.f};
      #pragma unroll 5
      for (int c = 0; c < 10; ++c) {   // x-part first (no cross-WG dependency)
        f16x8 a = fragq(xq[c]);
        B3 bb = ldB(W0x, EP, j, c * 32 + koff);
        aR = mf(a, bb.r, aR); aZ = mf(a, bb.z, aZ); aNX = mf(a, bb.n, aNX);
      }
      // need: all h1[s-1] (go0>=s); ring slot free (L1 finished s-RING: go1>=s-RING+1)
      wg_wait((s >= 1) ? g0p : nullptr, s,
              (s >= RING) ? g1p : nullptr, s - RING + 1);
      if (s >= 1) {
        HMat hA;
        load16_wait0(hA, h1ring + ((s - 1) & (RING - 1)) * HB, hoff);
        #pragma unroll 4
        for (int c = 0; c < 16; ++c) {
          f16x8 a = fragq(hA.q[c]);
          B3 bb = ldB(W0h, HH, j, c * 32 + koff);
          aR = mf(a, bb.r, aR); aZ = mf(a, bb.z, aZ); aNH = mf(a, bb.n, aNH);
        }
      }

      _Float16 (*tc)[16] = tile[s & 1][bsub];
      _Float16 (*tp)[16] = tile[(s + 1) & 1][bsub];
      #pragma unroll
      for (int rg = 0; rg < 4; ++rg) {
        const int rr = quad * 4 + rg;           // C/D row = quad*4+reg (within wave's 16)
        float r = sigf(aR[rg] + br);
        float z = sigf(aZ[rg] + bz);
        float n = tanhf(aNX[rg] + bnx + r * (aNH[rg] + bnh));
        float hp = (s >= 1) ? (float)tp[rr][l15] : 0.f;
        tc[rr][l15] = (_Float16)((1.f - z) * n + z * hp);
      }
      if (lane < 32) {                          // publish own 16 rows
        const int row = lane >> 1, seg = lane & 1;
        f16x8 v = *(const f16x8*)&tc[row][seg * 8];
        st16_llc(h1ring + (s & (RING - 1)) * HB + (size_t)(bsub * 16 + row) * HH + jb + seg * 8, v);
      }
      __builtin_amdgcn_s_waitcnt(0);            // drain own stores (release)
      if (lane == 0) st1_llc((char*)(flags0 + (size_t)s * 32 + w) + bsub, 1);
      if (s + 1 < T_STEPS)                      // batched x prefetch
        loadx10_wait(xq, x0 + (size_t)(s + 1) * BB * EP, xoff);
    }
  } else {
    const float br = bias1[j], bz = bias1[512 + j];
    const float bnx = bias1[1024 + j], bnh = bias1[1536 + j];
    for (int t = 0; t < T_STEPS; ++t) {
      f32x4 aR = {0.f,0.f,0.f,0.f}, aZ = {0.f,0.f,0.f,0.f};
      f32x4 aNX = {0.f,0.f,0.f,0.f}, aNH = {0.f,0.f,0.f,0.f};
      // phase 1: self-recurrence part (h2[t-1]) while L0 may still be finishing h1[t]
      wg_wait((t >= 1) ? g1p : nullptr, t, nullptr, 0);
      if (t >= 1) {
        HMat A2;
        load16_wait0(A2, h2buf + ((t - 1) & 1) * HB, hoff);
        #pragma unroll 4
        for (int c = 0; c < 16; ++c) {
          f16x8 a = fragq(A2.q[c]);
          B3 bb = ldB(W1h, HH, j, c * 32 + koff);
          aR = mf(a, bb.r, aR); aZ = mf(a, bb.z, aZ); aNH = mf(a, bb.n, aNH);
        }
      }
      // phase 2: h1[t] from layer 0
      wg_wait(g0p, t + 1, nullptr, 0);
      {
        HMat A1;
        load16_wait0(A1, h1ring + (t & (RING - 1)) * HB, hoff);
        #pragma unroll 4
        for (int c = 0; c < 16; ++c) {
          f16x8 a = fragq(A1.q[c]);
          B3 bb = ldB(W1x, HH, j, c * 32 + koff);
          aR = mf(a, bb.r, aR); aZ = mf(a, bb.z, aZ); aNX = mf(a, bb.n, aNX);
        }
      }

      _Float16 (*tc)[16] = tile[t & 1][bsub];
      _Float16 (*tp)[16] = tile[(t + 1) & 1][bsub];
      #pragma unroll
      for (int rg = 0; rg < 4; ++rg) {
        const int rr = quad * 4 + rg;
        float r = sigf(aR[rg] + br);
        float z = sigf(aZ[rg] + bz);
        float n = tanhf(aNX[rg] + bnx + r * (aNH[rg] + bnh));
        float hp = (t >= 1) ? (float)tp[rr][l15] : 0.f;
        tc[rr][l15] = (_Float16)((1.f - z) * n + z * hp);
      }
      if (lane < 32) {
        const int row = lane >> 1, seg = lane & 1;
        f16x8 v = *(const f16x8*)&tc[row][seg * 8];
        st16_llc(h2buf + (t & 1) * HB + (size_t)(bsub * 16 + row) * HH + jb + seg * 8, v);
      }
      __builtin_amdgcn_s_waitcnt(0);
      if (lane == 0) st1_llc((char*)(flags1 + (size_t)t * 32 + w) + bsub, 1);
      // pooled partial (off critical path, after publish): own 16 rows -> 16 cols
      if (lane < 16) {
        float sum = 0.f;
        #pragma unroll
        for (int r = 0; r < 16; ++r) sum += (float)tc[r][lane];
        atomicAdd(pooled + (size_t)t * HH + jb + lane, sum);   // raw sum over b; /64 in FC
      }
    }
  }
}

__global__ void fc_kernel(const float* __restrict__ pooled, const float* __restrict__ fcW,
                          const float* __restrict__ fcb, float* __restrict__ out) {
  const int t = blockIdx.x;
  const int lane = threadIdx.x;  // 64 = one wave
  float a0 = 0.f, a1 = 0.f, a2 = 0.f, a3 = 0.f, a4 = 0.f;
  for (int jj = lane; jj < HH; jj += 64) {
    float p = pooled[(size_t)t * HH + jj];
    a0 += p * fcW[jj];
    a1 += p * fcW[512 + jj];
    a2 += p * fcW[1024 + jj];
    a3 += p * fcW[1536 + jj];
    a4 += p * fcW[2048 + jj];
  }
  #pragma unroll
  for (int off = 32; off > 0; off >>= 1) {
    a0 += __shfl_down(a0, off, 64);
    a1 += __shfl_down(a1, off, 64);
    a2 += __shfl_down(a2, off, 64);
    a3 += __shfl_down(a3, off, 64);
    a4 += __shfl_down(a4, off, 64);
  }
  if (lane == 0) {
    const float sc = 1.f / 64.f;
    out[t * 5 + 0] = a0 * sc + fcb[0];
    out[t * 5 + 1] = a1 * sc + fcb[1];
    out[t * 5 + 2] = a2 * sc + fcb[2];
    out[t * 5 + 3] = a3 * sc + fcb[3];
    out[t * 5 + 4] = a4 * sc + fcb[4];
  }
}

extern "C" void kernel_launch(void* const* d_in, const int* in_sizes, int n_in,
                              void* d_out, int out_size, void* d_ws, size_t ws_size,
                              hipStream_t stream) {
  const int*   texts = (const int*)  d_in[0];
  const float* emb   = (const float*)d_in[1];
  const float* Wih0  = (const float*)d_in[2];
  const float* Whh0  = (const float*)d_in[3];
  const float* bih0  = (const float*)d_in[4];
  const float* bhh0  = (const float*)d_in[5];
  const float* Wih1  = (const float*)d_in[6];
  const float* Whh1  = (const float*)d_in[7];
  const float* bih1  = (const float*)d_in[8];
  const float* bhh1  = (const float*)d_in[9];
  const float* fcW   = (const float*)d_in[10];
  const float* fcb   = (const float*)d_in[11];
  float* out = (float*)d_out;

  char* ws = (char*)d_ws;
  int*      flags0 = (int*)ws;                        // 65536 B  [512][32] int
  int*      flags1 = (int*)(ws + 65536);              // 65536 B
  int*      go0    = (int*)(ws + 131072);             // 4096 B (64 WG-private lines)
  int*      go1    = (int*)(ws + 135168);             // 4096 B
  float*    pooled = (float*)(ws + 139264);           // 1048576 B [512][512] f32
  _Float16* h1ring = (_Float16*)(ws + 1187840);       // 262144 B (4 x 64x512 f16)
  _Float16* h2buf  = (_Float16*)(ws + 1449984);       // 131072 B (2 slots)
  _Float16* x0     = (_Float16*)(ws + 1581056);       // 20971520 B [512][64][320]
  _Float16* W0x    = (_Float16*)(ws + 22552576);      // 983040 B  [1536][320]
  _Float16* W0h    = (_Float16*)(ws + 23535616);      // 1572864 B [1536][512]
  _Float16* W1x    = (_Float16*)(ws + 25108480);      // 1572864 B
  _Float16* W1h    = (_Float16*)(ws + 26681344);      // 1572864 B
  float*    bias0  = (float*)(ws + 28254208);         // 8192 B (r,z,nx,nh)
  float*    bias1  = (float*)(ws + 28262400);         // 8192 B
  // total ws use: 28270592 B

  hipMemsetAsync(ws, 0, 1187840, stream);  // flags + go + pooled = zeros
  prep_x0<<<4096, 256, 0, stream>>>(texts, emb, x0);
  prep_w<<<1024, 256, 0, stream>>>(Wih0, Whh0, bih0, bhh0, Wih1, Whh1, bih1, bhh1,
                                   W0x, W0h, W1x, W1h, bias0, bias1);
  gru_persistent<<<65, 256, 0, stream>>>(x0, W0x, W0h, W1x, W1h, bias0, bias1,
                                         h1ring, h2buf, pooled, flags0, flags1, go0, go1);
  fc_kernel<<<512, 64, 0, stream>>>(pooled, fcW, fcb, out);
}